// Round 7
// baseline (322.236 us; speedup 1.0000x reference)
//
#include <hip/hip_runtime.h>

// GCN on MI355X (gfx950). n=100000, 1.6M edges, D 128/128/64.
// Round 16: strip middle-kernel waste; F kernels untouched (at scatter roofline).
//  - DROP col-bucket sort: measured null (F1 FETCH 182MB sorted vs 185 unsorted).
//    part2 is now a row-only counting sort (no NCB=13 machinery).
//  - boffs layout flipped to BLOCK-MAJOR: part1 publishes one contiguous
//    1.6KB run per block (was: column writes, 16 XCD-crossing writers per
//    64B line -> coherence RMW churn). part2's strided reads are tiny.
//  - NBUCK back to 392 (256-row buckets): part2 gather fragments 5 -> 10
//    edges; half the scan/search overhead per edge.
//  - Keep: merged k1 [part1||gemm0], zero global atomics, telescoping gb,
//    coop-shfl gather F kernels.
// Pipeline: wcvt -> K1[part1||gemm0] -> part2 -> F1 -> F2 -> spmm_out.

typedef unsigned int u32;
typedef unsigned short u16;
typedef __attribute__((ext_vector_type(8))) short bf16x8;
typedef __attribute__((ext_vector_type(4))) float f32x4;

constexpr int NN = 100000;
constexpr int NE = 1600000;
constexpr int RPB = 256;               // rows per bucket
constexpr int NBUCK = 392;             // 392 * 256 = 100352 = PAD
constexpr int PAD = 100352;
constexpr int BCAP = 4608;             // per-bucket edges (mean 4082)
constexpr int EPB = 4096;              // edges per part1 block
constexpr int P1B = (NE + EPB - 1) / EPB;   // 391 part1 blocks
constexpr int G0B = (NN + 63) / 64;         // 1563 gemm0 blocks
constexpr int BOS = NBUCK + 1;         // boffs row stride (block-major)

__device__ __forceinline__ u16 f2bf(float f) {   // RNE round to bf16
    u32 x = __float_as_uint(f);
    x += 0x7fffu + ((x >> 16) & 1u);
    return (u16)(x >> 16);
}

// ---------------------------------------------------------------------------
// Weight fp32 -> bf16 in B-fragment order.
// ---------------------------------------------------------------------------
__device__ __forceinline__ void wfrag_one(const float* __restrict__ W,
                                          u16* __restrict__ Wf, int total, int i)
{
    if (i < total) {
        const int j    = i & 7;
        const int lane = (i >> 3) & 63;
        const int kc   = (i >> 9) & 3;
        const int ct   = i >> 11;
        const int src  = (ct * 16 + (lane & 15)) * 128 + kc * 32 + (lane >> 4) * 8 + j;
        Wf[i] = f2bf(W[src]);
    }
}

__global__ __launch_bounds__(256)
void wcvt_kernel(const float* __restrict__ W0, const float* __restrict__ W1,
                 const float* __restrict__ W2, u16* __restrict__ wf0,
                 u16* __restrict__ wf1, u16* __restrict__ wf2)
{
    const int i = blockIdx.x * 256 + threadIdx.x;
    wfrag_one(W0, wf0, 128 * 128, i);
    wfrag_one(W1, wf1, 128 * 128, i);
    wfrag_one(W2, wf2, 64 * 128, i);
}

// ---------------------------------------------------------------------------
// K1: blocks [0, P1B) = part1 (block-local partition, no global atomics);
//     blocks [P1B, P1B+G0B) = gemm0 (t0 = x @ W0^T, bf16 MFMA).
// Shared LDS buffer sized for the gemm branch (17408 B; part1 uses ~5 KB).
// ---------------------------------------------------------------------------
__global__ __launch_bounds__(256)
void k1_kernel(const float* __restrict__ x, const u16* __restrict__ Wf,
               u16* __restrict__ Cb,
               const int* __restrict__ erow, const int* __restrict__ ecol,
               const float* __restrict__ eval,
               int2* __restrict__ part, int* __restrict__ boffs)
{
    __shared__ u16 smem[64 * 136];
    const int tid = threadIdx.x;

    if ((int)blockIdx.x < P1B) {
        // ---------------- part1 branch ----------------
        int* shist = (int*)smem;       // 512 ints
        int* sexcl = shist + 512;      // 512 ints (excl offsets -> cursors)
        int* sdat  = sexcl + 512;      // 256 ints
        const int blk = blockIdx.x;
        shist[tid] = 0; shist[tid + 256] = 0;
        __syncthreads();

        const int base = blk * EPB;
        int rr[EPB / 256];             // cache row ids (16 regs)
        #pragma unroll
        for (int j = 0; j < EPB / 256; ++j) {
            const int e = base + j * 256 + tid;
            rr[j] = (e < NE) ? erow[e] : -1;
            if (rr[j] >= 0) atomicAdd(&shist[rr[j] >> 8], 1);
        }
        __syncthreads();

        const int c0 = shist[2 * tid];
        const int c1 = shist[2 * tid + 1];
        const int tsum = c0 + c1;
        sdat[tid] = tsum;
        __syncthreads();
        #pragma unroll
        for (int off = 1; off < 256; off <<= 1) {
            const int v = (tid >= off) ? sdat[tid - off] : 0;
            __syncthreads();
            sdat[tid] += v;
            __syncthreads();
        }
        const int excl = sdat[tid] - tsum;
        sexcl[2 * tid]     = excl;
        sexcl[2 * tid + 1] = excl + c0;
        __syncthreads();

        // publish per-block offsets CONTIGUOUSLY (block-major boffs)
        for (int b = tid; b < NBUCK; b += 256)
            boffs[(size_t)blk * BOS + b] = sexcl[b];
        if (tid == 0) boffs[(size_t)blk * BOS + NBUCK] = sdat[255];
        __syncthreads();               // publish reads done before cursors move

        // scatter into the block's OWN 32KB region (L2-resident window)
        #pragma unroll
        for (int j = 0; j < EPB / 256; ++j) {
            const int r = rr[j];
            if (r >= 0) {
                const int e = base + j * 256 + tid;
                const int pos = atomicAdd(&sexcl[r >> 8], 1);
                part[(size_t)blk * EPB + pos] =
                    make_int2(((r & 255) << 17) | ecol[e], __float_as_int(eval[e]));
            }
        }
        return;
    }

    // ---------------- gemm0 branch ----------------
    constexpr int RS   = 136;
    constexpr int PADW = 136;          // DO=128 + 8
    u16* sA = smem;
    u16* sC = smem;
    const int w    = tid >> 6;
    const int lane = tid & 63;
    const int m    = lane & 15;
    const int q    = lane >> 4;
    const int rowBase = ((int)blockIdx.x - P1B) * 64;

    #pragma unroll
    for (int i = 0; i < 8; ++i) {
        const int g = (i * 256 + tid) * 4;
        const int r = g >> 7, c = g & 127;
        float4 v = make_float4(0.f, 0.f, 0.f, 0.f);
        if (rowBase + r < NN) v = *(const float4*)(x + (size_t)(rowBase + r) * 128 + c);
        u16* d = &sA[r * RS + c];
        d[0] = f2bf(v.x); d[1] = f2bf(v.y); d[2] = f2bf(v.z); d[3] = f2bf(v.w);
    }
    __syncthreads();

    bf16x8 afrag[4];
    #pragma unroll
    for (int kc = 0; kc < 4; ++kc)
        afrag[kc] = *(const bf16x8*)&sA[(w * 16 + m) * RS + kc * 32 + q * 8];
    __syncthreads();

    #pragma unroll
    for (int ct = 0; ct < 8; ++ct) {
        f32x4 acc = {0.f, 0.f, 0.f, 0.f};
        #pragma unroll
        for (int kc = 0; kc < 4; ++kc) {
            const bf16x8 b = *(const bf16x8*)(Wf + (((ct * 4 + kc) * 64) + lane) * 8);
            acc = __builtin_amdgcn_mfma_f32_16x16x32_bf16(afrag[kc], b, acc, 0, 0, 0);
        }
        #pragma unroll
        for (int r = 0; r < 4; ++r)
            sC[(w * 16 + q * 4 + r) * PADW + ct * 16 + m] = f2bf(acc[r]);
    }
    __syncthreads();

    const int g    = lane >> 2;
    const int cb   = (lane & 3) * 32;
    const int grow = rowBase + w * 16 + g;
    if (grow < NN) {
        #pragma unroll
        for (int i = 0; i < 4; ++i) {
            const int4 v = *(const int4*)&sC[(w * 16 + g) * PADW + cb + i * 8];
            *(int4*)(Cb + (size_t)grow * 128 + cb + i * 8) = v;
        }
    }
}

// ---------------------------------------------------------------------------
// part2: per 256-row bucket, ROW-ONLY counting sort.
//   Segment bounds from block-major boffs (adjacent pair per block);
//   512-wide scan -> cnt; gb via telescoping sum of boffs[k][b];
//   parallel binary-search gather into sbuf; row histogram + scan -> offs;
//   scatter directly into pce's L2-resident bucket window.
// ---------------------------------------------------------------------------
__global__ __launch_bounds__(256)
void part2_kernel(const int* __restrict__ boffs, const int2* __restrict__ part,
                  int* __restrict__ offs, int2* __restrict__ pce)
{
    __shared__ int2 sbuf[BCAP];        // 36864 B gathered bucket image
    __shared__ int slo[512];           // segment start offsets
    __shared__ int sinc[512];          // segment lengths -> inclusive scan
    __shared__ int scnt[256];          // row counts
    __shared__ int rowoff[256];        // row cursors (global positions)
    __shared__ int sdata[256];
    const int b = blockIdx.x;
    const int tid = threadIdx.x;

    // segment bounds (block-major: adjacent pair boffs[k][b], boffs[k][b+1])
    int gbp = 0;                       // partial sum for gb
    {
        int k = tid;
        int l0 = 0, ln = 0;
        if (k < P1B) {
            l0 = boffs[(size_t)k * BOS + b];
            ln = boffs[(size_t)k * BOS + b + 1] - l0;
        }
        slo[k] = l0; sinc[k] = ln; gbp += l0;
        k = tid + 256; l0 = 0; ln = 0;
        if (k < P1B) {
            l0 = boffs[(size_t)k * BOS + b];
            ln = boffs[(size_t)k * BOS + b + 1] - l0;
        }
        slo[k] = l0; sinc[k] = ln; gbp += l0;
    }
    scnt[tid] = 0;
    sdata[tid] = gbp;
    __syncthreads();
    #pragma unroll
    for (int off = 128; off > 0; off >>= 1) {
        if (tid < off) sdata[tid] += sdata[tid + off];
        __syncthreads();
    }
    const int gb = sdata[0];           // telescoping: sum_k boffs[k][b]
    __syncthreads();

    // Hillis-Steele inclusive scan over sinc[512] (256 threads, 2 elems each)
    for (int off = 1; off < 512; off <<= 1) {
        const int v0 = (tid >= off) ? sinc[tid - off] : 0;
        const int v1 = (tid + 256 >= off) ? sinc[tid + 256 - off] : 0;
        __syncthreads();
        sinc[tid]       += v0;
        sinc[tid + 256] += v1;
        __syncthreads();
    }
    const int cnt = sinc[511];

    // parallel gather: output index i -> segment k via 9-step binary search
    for (int i = tid; i < cnt; i += 256) {
        int k = 0;
        #pragma unroll
        for (int step = 256; step > 0; step >>= 1) {
            const int nk = k + step;
            if (nk <= 511 && sinc[nk - 1] <= i) k = nk;
        }
        const int loc = i - (k ? sinc[k - 1] : 0);
        sbuf[i] = part[(size_t)k * EPB + slo[k] + loc];
    }
    __syncthreads();

    // row histogram
    for (int i = tid; i < cnt; i += 256)
        atomicAdd(&scnt[((u32)sbuf[i].x) >> 17], 1);
    __syncthreads();

    // exclusive scan of row counts -> offs + cursors
    const int c = scnt[tid];
    sdata[tid] = c;
    __syncthreads();
    #pragma unroll
    for (int off = 1; off < 256; off <<= 1) {
        const int v = (tid >= off) ? sdata[tid - off] : 0;
        __syncthreads();
        sdata[tid] += v;
        __syncthreads();
    }
    const int excl = sdata[tid] - c;
    offs[b * RPB + tid] = gb + excl;
    rowoff[tid] = gb + excl;
    __syncthreads();

    // scatter directly into pce's bucket window (~37KB, L2-absorbed)
    for (int i = tid; i < cnt; i += 256) {
        const int2 ev = sbuf[i];
        const int rl = ((u32)ev.x) >> 17;
        const int pos = atomicAdd(&rowoff[rl], 1);
        pce[pos] = make_int2(ev.x & 0x1FFFF, ev.y);
    }
}

// ---------------------------------------------------------------------------
// Gather helpers (bf16 rows, fp32 accumulate).
// ---------------------------------------------------------------------------
template<int LPC>
__device__ __forceinline__ void load_row(const u16* p, u32* u) {
    if constexpr (LPC == 8) {
        const uint4 t = *(const uint4*)p;
        u[0] = t.x; u[1] = t.y; u[2] = t.z; u[3] = t.w;
    } else {
        const uint2 t = *(const uint2*)p;
        u[0] = t.x; u[1] = t.y;
    }
}

template<int LPC>
__device__ __forceinline__ void fma_row(float v, const u32* u, float* a) {
    #pragma unroll
    for (int j = 0; j < LPC / 2; ++j) {
        a[2*j]   = fmaf(v, __uint_as_float(u[j] << 16),         a[2*j]);
        a[2*j+1] = fmaf(v, __uint_as_float(u[j] & 0xffff0000u), a[2*j+1]);
    }
}

// ---------------------------------------------------------------------------
// Fused SpMM+GEMM: cooperative pce window load (16 edges / one 128B load per
// group) + shfl(16) broadcast -> 4-edge quads of back-to-back row loads ->
// relu(+residual) -> LDS A-tile -> mfma vs fragment-ordered Wf -> C store.
// MODE 1 also writes relu'd rows (h1) to Hout for the later residual.
// ---------------------------------------------------------------------------
template<int DO, int MODE>
__global__ __launch_bounds__(256)
void spmm_gemm(const int* __restrict__ offs, const int2* __restrict__ pce,
               const u16* __restrict__ Hb, const u16* __restrict__ Wf,
               const u16* __restrict__ Res, u16* __restrict__ Cb,
               u16* __restrict__ Hout)
{
    constexpr int RS   = 136;
    constexpr int PADW = DO + 8;
    __shared__ u16 smem[16 * 136];
    const int tid = threadIdx.x;
    const int ln  = tid & 15;
    const int rl  = tid >> 4;
    const int row = blockIdx.x * 16 + rl;

    const int s = offs[row];
    const int t = offs[row + 1];
    const u16* hbase = Hb + ln * 8;

    float a0[8], a1[8];
    #pragma unroll
    for (int j = 0; j < 8; ++j) { a0[j] = 0.f; a1[j] = 0.f; }

    for (int e = s; e < t; e += 16) {
        // cooperative load of this row's next 16 edges (one int2 per lane)
        int2 my = make_int2(0, 0);
        if (e + ln < t) my = pce[e + ln];
        const int rem = t - e;
        #pragma unroll
        for (int qd = 0; qd < 4; ++qd) {
            if (qd * 4 < rem) {
                const int c0 = __shfl(my.x, qd * 4 + 0, 16);
                const int v0 = __shfl(my.y, qd * 4 + 0, 16);
                const int c1 = __shfl(my.x, qd * 4 + 1, 16);
                const int v1 = __shfl(my.y, qd * 4 + 1, 16);
                const int c2 = __shfl(my.x, qd * 4 + 2, 16);
                const int v2 = __shfl(my.y, qd * 4 + 2, 16);
                const int c3 = __shfl(my.x, qd * 4 + 3, 16);
                const int v3 = __shfl(my.y, qd * 4 + 3, 16);
                u32 u0[4], u1[4], u2[4], u3[4];
                load_row<8>(hbase + (size_t)c0 * 128, u0);
                load_row<8>(hbase + (size_t)c1 * 128, u1);
                load_row<8>(hbase + (size_t)c2 * 128, u2);
                load_row<8>(hbase + (size_t)c3 * 128, u3);
                fma_row<8>(__int_as_float(v0), u0, a0);
                fma_row<8>(__int_as_float(v1), u1, a1);
                fma_row<8>(__int_as_float(v2), u2, a0);
                fma_row<8>(__int_as_float(v3), u3, a1);
            }
        }
    }
    #pragma unroll
    for (int j = 0; j < 8; ++j) a0[j] = fmaxf(a0[j] + a1[j], 0.f);

    if constexpr (MODE == 2) {
        u32 r[4];
        load_row<8>(Res + (size_t)row * 128 + ln * 8, r);
        #pragma unroll
        for (int j = 0; j < 4; ++j) {
            a0[2*j]   += __uint_as_float(r[j] << 16);
            a0[2*j+1] += __uint_as_float(r[j] & 0xffff0000u);
        }
    }
    u32 o[4];
    #pragma unroll
    for (int j = 0; j < 4; ++j)
        o[j] = (u32)f2bf(a0[2*j]) | ((u32)f2bf(a0[2*j+1]) << 16);
    const uint4 packed = make_uint4(o[0], o[1], o[2], o[3]);
    *(uint4*)&smem[rl * RS + ln * 8] = packed;
    if constexpr (MODE == 1)
        *(uint4*)(Hout + (size_t)row * 128 + ln * 8) = packed;
    __syncthreads();

    constexpr int TPW = DO / 64;
    const int w    = tid >> 6;
    const int lane = tid & 63;
    const int m    = lane & 15;
    const int q    = lane >> 4;

    bf16x8 afrag[4];
    #pragma unroll
    for (int kc = 0; kc < 4; ++kc)
        afrag[kc] = *(const bf16x8*)&smem[m * RS + kc * 32 + q * 8];

    f32x4 acc[TPW];
    #pragma unroll
    for (int tw = 0; tw < TPW; ++tw) {
        const int ct = w * TPW + tw;
        acc[tw] = (f32x4){0.f, 0.f, 0.f, 0.f};
        #pragma unroll
        for (int kc = 0; kc < 4; ++kc) {
            const bf16x8 b = *(const bf16x8*)(Wf + (((ct * 4 + kc) * 64) + lane) * 8);
            acc[tw] = __builtin_amdgcn_mfma_f32_16x16x32_bf16(afrag[kc], b, acc[tw], 0, 0, 0);
        }
    }
    __syncthreads();

    #pragma unroll
    for (int tw = 0; tw < TPW; ++tw) {
        const int ct = w * TPW + tw;
        #pragma unroll
        for (int r = 0; r < 4; ++r)
            smem[(q * 4 + r) * PADW + ct * 16 + m] = f2bf(acc[tw][r]);
    }
    __syncthreads();

    if (DO == 128 || tid < 128) {
        const int g = tid * 8;
        const int r = g / DO;
        const int c = g % DO;
        const int4 v = *(const int4*)&smem[r * PADW + c];
        *(int4*)(Cb + ((size_t)blockIdx.x * 16 + r) * DO + c) = v;
    }
}

// ---------------------------------------------------------------------------
// Final CSR SpMM (layer 3): gather t2 (D=64), cooperative pce + shfl, fp32 out.
// ---------------------------------------------------------------------------
__global__ __launch_bounds__(256)
void spmm_out(const int* __restrict__ offs, const int2* __restrict__ pce,
              const u16* __restrict__ Hb, float* __restrict__ Y)
{
    const int ln  = threadIdx.x & 15;
    const int row = blockIdx.x * 16 + (threadIdx.x >> 4);
    if (row >= NN) return;
    const int s = offs[row];
    const int t = offs[row + 1];
    const u16* hbase = Hb + ln * 4;

    float a0[4], a1[4];
    #pragma unroll
    for (int j = 0; j < 4; ++j) { a0[j] = 0.f; a1[j] = 0.f; }

    for (int e = s; e < t; e += 16) {
        int2 my = make_int2(0, 0);
        if (e + ln < t) my = pce[e + ln];
        const int rem = t - e;
        #pragma unroll
        for (int qd = 0; qd < 4; ++qd) {
            if (qd * 4 < rem) {
                const int c0 = __shfl(my.x, qd * 4 + 0, 16);
                const int v0 = __shfl(my.y, qd * 4 + 0, 16);
                const int c1 = __shfl(my.x, qd * 4 + 1, 16);
                const int v1 = __shfl(my.y, qd * 4 + 1, 16);
                const int c2 = __shfl(my.x, qd * 4 + 2, 16);
                const int v2 = __shfl(my.y, qd * 4 + 2, 16);
                const int c3 = __shfl(my.x, qd * 4 + 3, 16);
                const int v3 = __shfl(my.y, qd * 4 + 3, 16);
                u32 u0[2], u1[2], u2[2], u3[2];
                load_row<4>(hbase + (size_t)c0 * 64, u0);
                load_row<4>(hbase + (size_t)c1 * 64, u1);
                load_row<4>(hbase + (size_t)c2 * 64, u2);
                load_row<4>(hbase + (size_t)c3 * 64, u3);
                fma_row<4>(__int_as_float(v0), u0, a0);
                fma_row<4>(__int_as_float(v1), u1, a1);
                fma_row<4>(__int_as_float(v2), u2, a0);
                fma_row<4>(__int_as_float(v3), u3, a1);
            }
        }
    }
    #pragma unroll
    for (int j = 0; j < 4; ++j) a0[j] += a1[j];
    *(float4*)(Y + (size_t)row * 64 + ln * 4) = make_float4(a0[0], a0[1], a0[2], a0[3]);
}

extern "C" void kernel_launch(void* const* d_in, const int* in_sizes, int n_in,
                              void* d_out, int out_size, void* d_ws, size_t ws_size,
                              hipStream_t stream) {
    const float* x    = (const float*)d_in[0];
    const int*   erow = (const int*)  d_in[1];
    const int*   ecol = (const int*)  d_in[2];
    const float* eval = (const float*)d_in[3];
    const float* W0   = (const float*)d_in[4];
    const float* W1   = (const float*)d_in[5];
    const float* W2   = (const float*)d_in[6];
    float* out = (float*)d_out;

    char* p = (char*)d_ws;
    const size_t BUFB = (size_t)NN * 128 * sizeof(u16);   // 25.6 MB
    u16* t0b  = (u16*)p;  p += BUFB;     // t0; reused for t2 (t0 dead by then)
    u16* t1b  = (u16*)p;  p += BUFB;
    u16* h1b  = (u16*)p;  p += BUFB;
    u16* wf0  = (u16*)p;  p += 128 * 128 * 2;
    u16* wf1  = (u16*)p;  p += 128 * 128 * 2;
    u16* wf2  = (u16*)p;  p += 64 * 128 * 2;
    int* boffs  = (int*)p; p += (size_t)P1B * BOS * 4;    // 615 KB (block-major)
    int* offs   = (int*)p; p += ((size_t)PAD + 256) * 4;
    int2* part  = (int2*)p; p += (size_t)P1B * EPB * 8;   // 12.81 MB
    int2* pce   = (int2*)p;                               // 12.8 MB

    const dim3 blk(256);
    const int rowBlocks = NN / 16;     // 6250

    wcvt_kernel<<<64, blk, 0, stream>>>(W0, W1, W2, wf0, wf1, wf2);
    k1_kernel  <<<P1B + G0B, blk, 0, stream>>>(x, wf0, t0b, erow, ecol, eval, part, boffs);
    part2_kernel<<<NBUCK, blk, 0, stream>>>(boffs, part, offs, pce);
    spmm_gemm<128, 1><<<rowBlocks, blk, 0, stream>>>(offs, pce, t0b, wf1, nullptr, t1b, h1b);
    spmm_gemm<64, 2><<<rowBlocks, blk, 0, stream>>>(offs, pce, t1b, wf2, h1b, t0b, nullptr);
    spmm_out<<<rowBlocks, blk, 0, stream>>>(offs, pce, t0b, out);
}

// Round 8
// 312.162 us; speedup vs baseline: 1.0323x; 1.0323x over previous
//
#include <hip/hip_runtime.h>

// GCN on MI355X (gfx950). n=100000, 1.6M edges, D 128/128/64.
// Round 17: dependency-graph overlap, attempt 2.
//   part2 depends only on part1 (not gemm0); gemm0 depends only on wcvt.
//   Pipeline: wcvt -> part1 -> K2[part2 || gemm0] -> F1 -> F2 -> out.
//   (was: [part1||gemm0] -> part2; part2 ran serial for ~35-50us)
//  - part1 & part2: 512 threads/block (512-wide scans become direct,
//    2x per-block throughput; part1's 391 blocks = 12 waves/CU).
//  - gemm0 re-geared to 128 rows/block (512 thr, 8 waves, 782 blocks) so it
//    can share K2's dispatch with part2.
//  - F kernels / wcvt unchanged (F's at scattered-64B HBM roofline, 47.8%).
// Falsifier carried: if part1 standalone >= 40us, its LDS atomics are the
// hidden invariant cost -> rewrite histogram next.

typedef unsigned int u32;
typedef unsigned short u16;
typedef __attribute__((ext_vector_type(8))) short bf16x8;
typedef __attribute__((ext_vector_type(4))) float f32x4;

constexpr int NN = 100000;
constexpr int NE = 1600000;
constexpr int RPB = 256;               // rows per bucket
constexpr int NBUCK = 392;             // 392 * 256 = 100352 = PAD
constexpr int PAD = 100352;
constexpr int BCAP = 4608;             // per-bucket edges (mean 4082)
constexpr int EPB = 4096;              // edges per part1 block
constexpr int P1B = (NE + EPB - 1) / EPB;   // 391 part1 blocks
constexpr int G0B2 = (NN + 127) / 128;      // 782 gemm0 blocks (128 rows)
constexpr int BOS = NBUCK + 1;         // boffs row stride (block-major)

__device__ __forceinline__ u16 f2bf(float f) {   // RNE round to bf16
    u32 x = __float_as_uint(f);
    x += 0x7fffu + ((x >> 16) & 1u);
    return (u16)(x >> 16);
}

// ---------------------------------------------------------------------------
// Weight fp32 -> bf16 in B-fragment order.
// ---------------------------------------------------------------------------
__device__ __forceinline__ void wfrag_one(const float* __restrict__ W,
                                          u16* __restrict__ Wf, int total, int i)
{
    if (i < total) {
        const int j    = i & 7;
        const int lane = (i >> 3) & 63;
        const int kc   = (i >> 9) & 3;
        const int ct   = i >> 11;
        const int src  = (ct * 16 + (lane & 15)) * 128 + kc * 32 + (lane >> 4) * 8 + j;
        Wf[i] = f2bf(W[src]);
    }
}

__global__ __launch_bounds__(256)
void wcvt_kernel(const float* __restrict__ W0, const float* __restrict__ W1,
                 const float* __restrict__ W2, u16* __restrict__ wf0,
                 u16* __restrict__ wf1, u16* __restrict__ wf2)
{
    const int i = blockIdx.x * 256 + threadIdx.x;
    wfrag_one(W0, wf0, 128 * 128, i);
    wfrag_one(W1, wf1, 128 * 128, i);
    wfrag_one(W2, wf2, 64 * 128, i);
}

// ---------------------------------------------------------------------------
// part1 (512 threads): block-local bucket partition, no global atomics.
// LDS histogram (512 buckets) -> direct 512-wide scan -> contiguous
// block-major boffs publish -> scatter into the block's own 32KB region.
// ---------------------------------------------------------------------------
__global__ __launch_bounds__(512)
void part1_kernel(const int* __restrict__ erow, const int* __restrict__ ecol,
                  const float* __restrict__ eval,
                  int2* __restrict__ part, int* __restrict__ boffs)
{
    __shared__ int shist[512];
    __shared__ int sexcl[512];
    __shared__ int ssc[512];
    const int tid = threadIdx.x;
    const int blk = blockIdx.x;

    shist[tid] = 0;
    __syncthreads();

    const int base = blk * EPB;
    int rr[EPB / 512];                 // 8 cached row ids
    #pragma unroll
    for (int j = 0; j < EPB / 512; ++j) {
        const int e = base + j * 512 + tid;
        rr[j] = (e < NE) ? erow[e] : -1;
        if (rr[j] >= 0) atomicAdd(&shist[rr[j] >> 8], 1);
    }
    __syncthreads();

    const int cval = shist[tid];
    ssc[tid] = cval;
    __syncthreads();
    #pragma unroll
    for (int off = 1; off < 512; off <<= 1) {
        const int v = (tid >= off) ? ssc[tid - off] : 0;
        __syncthreads();
        ssc[tid] += v;
        __syncthreads();
    }
    const int excl = ssc[tid] - cval;
    sexcl[tid] = excl;
    if (tid < NBUCK) boffs[(size_t)blk * BOS + tid] = excl;
    if (tid == 0)    boffs[(size_t)blk * BOS + NBUCK] = ssc[511];
    __syncthreads();

    #pragma unroll
    for (int j = 0; j < EPB / 512; ++j) {
        const int r = rr[j];
        if (r >= 0) {
            const int e = base + j * 512 + tid;
            const int pos = atomicAdd(&sexcl[r >> 8], 1);
            part[(size_t)blk * EPB + pos] =
                make_int2(((r & 255) << 17) | ecol[e], __float_as_int(eval[e]));
        }
    }
}

// ---------------------------------------------------------------------------
// K2 (512 threads): blocks [0, NBUCK) = part2 (row counting sort);
//                   blocks [NBUCK, NBUCK+G0B2) = gemm0, 128 rows/block.
// part2 (scatter/latency-bound) overlaps gemm0 (stream/MFMA-bound).
// ---------------------------------------------------------------------------
__global__ __launch_bounds__(512)
void k2_kernel(const float* __restrict__ x, const u16* __restrict__ Wf,
               u16* __restrict__ Cb,
               const int* __restrict__ boffs, const int2* __restrict__ part,
               int* __restrict__ offs, int2* __restrict__ pce)
{
    __shared__ __align__(16) long long smem8[5632];   // 45056 B shared pool
    const int tid = threadIdx.x;

    if ((int)blockIdx.x < NBUCK) {
        // ---------------- part2 branch ----------------
        int2* sbuf  = (int2*)smem8;                     // BCAP int2 (36864 B)
        int* slo    = (int*)(sbuf + BCAP);              // 512
        int* sinc   = slo + 512;                        // 512
        int* scnt   = sinc + 512;                       // 256
        int* rowoff = scnt + 256;                       // 256
        int* sdata  = rowoff + 256;                     // 512
        const int b = blockIdx.x;

        // segment bounds (block-major boffs: adjacent pair per block k)
        int l0 = 0, ln = 0;
        if (tid < P1B) {
            l0 = boffs[(size_t)tid * BOS + b];
            ln = boffs[(size_t)tid * BOS + b + 1] - l0;
        }
        slo[tid] = l0; sinc[tid] = ln;
        if (tid < 256) scnt[tid] = 0;
        sdata[tid] = l0;               // gb = telescoping sum of boffs[k][b]
        __syncthreads();
        #pragma unroll
        for (int off = 256; off > 0; off >>= 1) {
            if (tid < off) sdata[tid] += sdata[tid + off];
            __syncthreads();
        }
        const int gb = sdata[0];
        __syncthreads();

        // inclusive scan over sinc[512]
        #pragma unroll
        for (int off = 1; off < 512; off <<= 1) {
            const int v = (tid >= off) ? sinc[tid - off] : 0;
            __syncthreads();
            sinc[tid] += v;
            __syncthreads();
        }
        const int cnt = sinc[511];

        // parallel gather: output index i -> segment k via binary search
        for (int i = tid; i < cnt; i += 512) {
            int k = 0;
            #pragma unroll
            for (int step = 256; step > 0; step >>= 1) {
                const int nk = k + step;
                if (nk <= 511 && sinc[nk - 1] <= i) k = nk;
            }
            const int loc = i - (k ? sinc[k - 1] : 0);
            sbuf[i] = part[(size_t)k * EPB + slo[k] + loc];
        }
        __syncthreads();

        // row histogram
        for (int i = tid; i < cnt; i += 512)
            atomicAdd(&scnt[((u32)sbuf[i].x) >> 17], 1);
        __syncthreads();

        // scan of 256 row counts (512 threads execute barriers)
        const int c = (tid < 256) ? scnt[tid] : 0;
        sdata[tid] = c;
        __syncthreads();
        #pragma unroll
        for (int off = 1; off < 256; off <<= 1) {
            const int v = (tid >= off && tid < 256) ? sdata[tid - off] : 0;
            __syncthreads();
            if (tid < 256) sdata[tid] += v;
            __syncthreads();
        }
        if (tid < 256) {
            const int excl = sdata[tid] - c;
            offs[b * RPB + tid] = gb + excl;
            rowoff[tid] = gb + excl;
        }
        __syncthreads();

        // scatter into pce's ~37KB bucket window (L2-absorbed)
        for (int i = tid; i < cnt; i += 512) {
            const int2 ev = sbuf[i];
            const int pos = atomicAdd(&rowoff[((u32)ev.x) >> 17], 1);
            pce[pos] = make_int2(ev.x & 0x1FFFF, ev.y);
        }
        return;
    }

    // ---------------- gemm0 branch: 128 rows/block ----------------
    constexpr int RS   = 136;
    constexpr int PADW = 136;
    u16* sA = (u16*)smem8;             // 128*136 u16 = 34816 B
    u16* sC = sA;
    const int w    = tid >> 6;         // 0..7
    const int lane = tid & 63;
    const int m    = lane & 15;
    const int q    = lane >> 4;
    const int rowBase = ((int)blockIdx.x - NBUCK) * 128;

    #pragma unroll
    for (int i = 0; i < 8; ++i) {
        const int g = (i * 512 + tid) * 4;
        const int r = g >> 7, c = g & 127;
        float4 v = make_float4(0.f, 0.f, 0.f, 0.f);
        if (rowBase + r < NN) v = *(const float4*)(x + (size_t)(rowBase + r) * 128 + c);
        u16* d = &sA[r * RS + c];
        d[0] = f2bf(v.x); d[1] = f2bf(v.y); d[2] = f2bf(v.z); d[3] = f2bf(v.w);
    }
    __syncthreads();

    bf16x8 afrag[4];
    #pragma unroll
    for (int kc = 0; kc < 4; ++kc)
        afrag[kc] = *(const bf16x8*)&sA[(w * 16 + m) * RS + kc * 32 + q * 8];
    __syncthreads();

    #pragma unroll
    for (int ct = 0; ct < 8; ++ct) {
        f32x4 acc = {0.f, 0.f, 0.f, 0.f};
        #pragma unroll
        for (int kc = 0; kc < 4; ++kc) {
            const bf16x8 bfr = *(const bf16x8*)(Wf + (((ct * 4 + kc) * 64) + lane) * 8);
            acc = __builtin_amdgcn_mfma_f32_16x16x32_bf16(afrag[kc], bfr, acc, 0, 0, 0);
        }
        #pragma unroll
        for (int r = 0; r < 4; ++r)
            sC[(w * 16 + q * 4 + r) * PADW + ct * 16 + m] = f2bf(acc[r]);
    }
    __syncthreads();

    const int g    = lane >> 2;
    const int cb   = (lane & 3) * 32;
    const int grow = rowBase + w * 16 + g;
    if (grow < NN) {
        #pragma unroll
        for (int i = 0; i < 4; ++i) {
            const int4 v = *(const int4*)&sC[(w * 16 + g) * PADW + cb + i * 8];
            *(int4*)(Cb + (size_t)grow * 128 + cb + i * 8) = v;
        }
    }
}

// ---------------------------------------------------------------------------
// Gather helpers (bf16 rows, fp32 accumulate).
// ---------------------------------------------------------------------------
template<int LPC>
__device__ __forceinline__ void load_row(const u16* p, u32* u) {
    if constexpr (LPC == 8) {
        const uint4 t = *(const uint4*)p;
        u[0] = t.x; u[1] = t.y; u[2] = t.z; u[3] = t.w;
    } else {
        const uint2 t = *(const uint2*)p;
        u[0] = t.x; u[1] = t.y;
    }
}

template<int LPC>
__device__ __forceinline__ void fma_row(float v, const u32* u, float* a) {
    #pragma unroll
    for (int j = 0; j < LPC / 2; ++j) {
        a[2*j]   = fmaf(v, __uint_as_float(u[j] << 16),         a[2*j]);
        a[2*j+1] = fmaf(v, __uint_as_float(u[j] & 0xffff0000u), a[2*j+1]);
    }
}

// ---------------------------------------------------------------------------
// Fused SpMM+GEMM: cooperative pce window load + shfl(16) broadcast ->
// 4-edge quads of back-to-back row loads -> relu(+residual) -> LDS A-tile
// -> mfma vs fragment-ordered Wf -> coalesced C store.
// MODE 1 also writes relu'd rows (h1) to Hout for the later residual.
// ---------------------------------------------------------------------------
template<int DO, int MODE>
__global__ __launch_bounds__(256)
void spmm_gemm(const int* __restrict__ offs, const int2* __restrict__ pce,
               const u16* __restrict__ Hb, const u16* __restrict__ Wf,
               const u16* __restrict__ Res, u16* __restrict__ Cb,
               u16* __restrict__ Hout)
{
    constexpr int RS   = 136;
    constexpr int PADW = DO + 8;
    __shared__ u16 smem[16 * 136];
    const int tid = threadIdx.x;
    const int ln  = tid & 15;
    const int rl  = tid >> 4;
    const int row = blockIdx.x * 16 + rl;

    const int s = offs[row];
    const int t = offs[row + 1];
    const u16* hbase = Hb + ln * 8;

    float a0[8], a1[8];
    #pragma unroll
    for (int j = 0; j < 8; ++j) { a0[j] = 0.f; a1[j] = 0.f; }

    for (int e = s; e < t; e += 16) {
        int2 my = make_int2(0, 0);
        if (e + ln < t) my = pce[e + ln];
        const int rem = t - e;
        #pragma unroll
        for (int qd = 0; qd < 4; ++qd) {
            if (qd * 4 < rem) {
                const int c0 = __shfl(my.x, qd * 4 + 0, 16);
                const int v0 = __shfl(my.y, qd * 4 + 0, 16);
                const int c1 = __shfl(my.x, qd * 4 + 1, 16);
                const int v1 = __shfl(my.y, qd * 4 + 1, 16);
                const int c2 = __shfl(my.x, qd * 4 + 2, 16);
                const int v2 = __shfl(my.y, qd * 4 + 2, 16);
                const int c3 = __shfl(my.x, qd * 4 + 3, 16);
                const int v3 = __shfl(my.y, qd * 4 + 3, 16);
                u32 u0[4], u1[4], u2[4], u3[4];
                load_row<8>(hbase + (size_t)c0 * 128, u0);
                load_row<8>(hbase + (size_t)c1 * 128, u1);
                load_row<8>(hbase + (size_t)c2 * 128, u2);
                load_row<8>(hbase + (size_t)c3 * 128, u3);
                fma_row<8>(__int_as_float(v0), u0, a0);
                fma_row<8>(__int_as_float(v1), u1, a1);
                fma_row<8>(__int_as_float(v2), u2, a0);
                fma_row<8>(__int_as_float(v3), u3, a1);
            }
        }
    }
    #pragma unroll
    for (int j = 0; j < 8; ++j) a0[j] = fmaxf(a0[j] + a1[j], 0.f);

    if constexpr (MODE == 2) {
        u32 r[4];
        load_row<8>(Res + (size_t)row * 128 + ln * 8, r);
        #pragma unroll
        for (int j = 0; j < 4; ++j) {
            a0[2*j]   += __uint_as_float(r[j] << 16);
            a0[2*j+1] += __uint_as_float(r[j] & 0xffff0000u);
        }
    }
    u32 o[4];
    #pragma unroll
    for (int j = 0; j < 4; ++j)
        o[j] = (u32)f2bf(a0[2*j]) | ((u32)f2bf(a0[2*j+1]) << 16);
    const uint4 packed = make_uint4(o[0], o[1], o[2], o[3]);
    *(uint4*)&smem[rl * RS + ln * 8] = packed;
    if constexpr (MODE == 1)
        *(uint4*)(Hout + (size_t)row * 128 + ln * 8) = packed;
    __syncthreads();

    constexpr int TPW = DO / 64;
    const int w    = tid >> 6;
    const int lane = tid & 63;
    const int m    = lane & 15;
    const int q    = lane >> 4;

    bf16x8 afrag[4];
    #pragma unroll
    for (int kc = 0; kc < 4; ++kc)
        afrag[kc] = *(const bf16x8*)&smem[m * RS + kc * 32 + q * 8];

    f32x4 acc[TPW];
    #pragma unroll
    for (int tw = 0; tw < TPW; ++tw) {
        const int ct = w * TPW + tw;
        acc[tw] = (f32x4){0.f, 0.f, 0.f, 0.f};
        #pragma unroll
        for (int kc = 0; kc < 4; ++kc) {
            const bf16x8 b = *(const bf16x8*)(Wf + (((ct * 4 + kc) * 64) + lane) * 8);
            acc[tw] = __builtin_amdgcn_mfma_f32_16x16x32_bf16(afrag[kc], b, acc[tw], 0, 0, 0);
        }
    }
    __syncthreads();

    #pragma unroll
    for (int tw = 0; tw < TPW; ++tw) {
        const int ct = w * TPW + tw;
        #pragma unroll
        for (int r = 0; r < 4; ++r)
            smem[(q * 4 + r) * PADW + ct * 16 + m] = f2bf(acc[tw][r]);
    }
    __syncthreads();

    if (DO == 128 || tid < 128) {
        const int g = tid * 8;
        const int r = g / DO;
        const int c = g % DO;
        const int4 v = *(const int4*)&smem[r * PADW + c];
        *(int4*)(Cb + ((size_t)blockIdx.x * 16 + r) * DO + c) = v;
    }
}

// ---------------------------------------------------------------------------
// Final CSR SpMM (layer 3): gather t2 (D=64), cooperative pce + shfl, fp32 out.
// ---------------------------------------------------------------------------
__global__ __launch_bounds__(256)
void spmm_out(const int* __restrict__ offs, const int2* __restrict__ pce,
              const u16* __restrict__ Hb, float* __restrict__ Y)
{
    const int ln  = threadIdx.x & 15;
    const int row = blockIdx.x * 16 + (threadIdx.x >> 4);
    if (row >= NN) return;
    const int s = offs[row];
    const int t = offs[row + 1];
    const u16* hbase = Hb + ln * 4;

    float a0[4], a1[4];
    #pragma unroll
    for (int j = 0; j < 4; ++j) { a0[j] = 0.f; a1[j] = 0.f; }

    for (int e = s; e < t; e += 16) {
        int2 my = make_int2(0, 0);
        if (e + ln < t) my = pce[e + ln];
        const int rem = t - e;
        #pragma unroll
        for (int qd = 0; qd < 4; ++qd) {
            if (qd * 4 < rem) {
                const int c0 = __shfl(my.x, qd * 4 + 0, 16);
                const int v0 = __shfl(my.y, qd * 4 + 0, 16);
                const int c1 = __shfl(my.x, qd * 4 + 1, 16);
                const int v1 = __shfl(my.y, qd * 4 + 1, 16);
                const int c2 = __shfl(my.x, qd * 4 + 2, 16);
                const int v2 = __shfl(my.y, qd * 4 + 2, 16);
                const int c3 = __shfl(my.x, qd * 4 + 3, 16);
                const int v3 = __shfl(my.y, qd * 4 + 3, 16);
                u32 u0[2], u1[2], u2[2], u3[2];
                load_row<4>(hbase + (size_t)c0 * 64, u0);
                load_row<4>(hbase + (size_t)c1 * 64, u1);
                load_row<4>(hbase + (size_t)c2 * 64, u2);
                load_row<4>(hbase + (size_t)c3 * 64, u3);
                fma_row<4>(__int_as_float(v0), u0, a0);
                fma_row<4>(__int_as_float(v1), u1, a1);
                fma_row<4>(__int_as_float(v2), u2, a0);
                fma_row<4>(__int_as_float(v3), u3, a1);
            }
        }
    }
    #pragma unroll
    for (int j = 0; j < 4; ++j) a0[j] += a1[j];
    *(float4*)(Y + (size_t)row * 64 + ln * 4) = make_float4(a0[0], a0[1], a0[2], a0[3]);
}

extern "C" void kernel_launch(void* const* d_in, const int* in_sizes, int n_in,
                              void* d_out, int out_size, void* d_ws, size_t ws_size,
                              hipStream_t stream) {
    const float* x    = (const float*)d_in[0];
    const int*   erow = (const int*)  d_in[1];
    const int*   ecol = (const int*)  d_in[2];
    const float* eval = (const float*)d_in[3];
    const float* W0   = (const float*)d_in[4];
    const float* W1   = (const float*)d_in[5];
    const float* W2   = (const float*)d_in[6];
    float* out = (float*)d_out;

    char* p = (char*)d_ws;
    const size_t BUFB = (size_t)NN * 128 * sizeof(u16);   // 25.6 MB
    u16* t0b  = (u16*)p;  p += BUFB;     // t0; reused for t2 (t0 dead by then)
    u16* t1b  = (u16*)p;  p += BUFB;
    u16* h1b  = (u16*)p;  p += BUFB;
    u16* wf0  = (u16*)p;  p += 128 * 128 * 2;
    u16* wf1  = (u16*)p;  p += 128 * 128 * 2;
    u16* wf2  = (u16*)p;  p += 64 * 128 * 2;
    int* boffs  = (int*)p; p += (size_t)P1B * BOS * 4;    // 615 KB (block-major)
    int* offs   = (int*)p; p += ((size_t)PAD + 256) * 4;
    int2* part  = (int2*)p; p += (size_t)P1B * EPB * 8;   // 12.81 MB
    int2* pce   = (int2*)p;                               // 12.8 MB

    const int rowBlocks = NN / 16;     // 6250

    wcvt_kernel <<<64, dim3(256), 0, stream>>>(W0, W1, W2, wf0, wf1, wf2);
    part1_kernel<<<P1B, dim3(512), 0, stream>>>(erow, ecol, eval, part, boffs);
    k2_kernel   <<<NBUCK + G0B2, dim3(512), 0, stream>>>(x, wf0, t0b, boffs, part, offs, pce);
    spmm_gemm<128, 1><<<rowBlocks, dim3(256), 0, stream>>>(offs, pce, t0b, wf1, nullptr, t1b, h1b);
    spmm_gemm<64, 2><<<rowBlocks, dim3(256), 0, stream>>>(offs, pce, t1b, wf2, h1b, t0b, nullptr);
    spmm_out<<<rowBlocks, dim3(256), 0, stream>>>(offs, pce, t0b, out);
}

// Round 11
// 310.470 us; speedup vs baseline: 1.0379x; 1.0054x over previous
//
#include <hip/hip_runtime.h>

// GCN on MI355X (gfx950). n=100000, 1.6M edges, D 128/128/64.
// Round 19: bisection round. R18's bundle (k0 merge + EPB 8192 + prefetch)
// killed the container 4x; R17 passed. This is the KNOWN-GOOD R17 structure
// with exactly ONE R18 change re-applied: software-pipelined pce window
// prefetch in the F kernels (local change, guarded loads, no new barriers).
//  - If this passes: measures prefetch in isolation; k0 consolidation gets
//    retried separately next.
//  - If this also kills the container: failures were node-level infra.
// Pipeline: wcvt -> part1 -> K2[part2||gemm0] -> F1 -> F2 -> spmm_out.

typedef unsigned int u32;
typedef unsigned short u16;
typedef __attribute__((ext_vector_type(8))) short bf16x8;
typedef __attribute__((ext_vector_type(4))) float f32x4;

constexpr int NN = 100000;
constexpr int NE = 1600000;
constexpr int RPB = 256;               // rows per bucket
constexpr int NBUCK = 392;             // 392 * 256 = 100352 = PAD
constexpr int PAD = 100352;
constexpr int BCAP = 4608;             // per-bucket edges (mean 4082)
constexpr int EPB = 4096;              // edges per part1 block
constexpr int P1B = (NE + EPB - 1) / EPB;   // 391 part1 blocks
constexpr int G0B2 = (NN + 127) / 128;      // 782 gemm0 blocks (128 rows)
constexpr int BOS = NBUCK + 1;         // boffs row stride (block-major)

__device__ __forceinline__ u16 f2bf(float f) {   // RNE round to bf16
    u32 x = __float_as_uint(f);
    x += 0x7fffu + ((x >> 16) & 1u);
    return (u16)(x >> 16);
}

// ---------------------------------------------------------------------------
// Weight fp32 -> bf16 in B-fragment order.
// ---------------------------------------------------------------------------
__device__ __forceinline__ void wfrag_one(const float* __restrict__ W,
                                          u16* __restrict__ Wf, int total, int i)
{
    if (i < total) {
        const int j    = i & 7;
        const int lane = (i >> 3) & 63;
        const int kc   = (i >> 9) & 3;
        const int ct   = i >> 11;
        const int src  = (ct * 16 + (lane & 15)) * 128 + kc * 32 + (lane >> 4) * 8 + j;
        Wf[i] = f2bf(W[src]);
    }
}

__global__ __launch_bounds__(256)
void wcvt_kernel(const float* __restrict__ W0, const float* __restrict__ W1,
                 const float* __restrict__ W2, u16* __restrict__ wf0,
                 u16* __restrict__ wf1, u16* __restrict__ wf2)
{
    const int i = blockIdx.x * 256 + threadIdx.x;
    wfrag_one(W0, wf0, 128 * 128, i);
    wfrag_one(W1, wf1, 128 * 128, i);
    wfrag_one(W2, wf2, 64 * 128, i);
}

// ---------------------------------------------------------------------------
// part1 (512 threads): block-local bucket partition, no global atomics.
// LDS histogram (392 buckets in 512 slots) -> direct 512-wide scan ->
// contiguous block-major boffs publish -> scatter into the block's own
// 32KB region (L2-resident window).
// ---------------------------------------------------------------------------
__global__ __launch_bounds__(512)
void part1_kernel(const int* __restrict__ erow, const int* __restrict__ ecol,
                  const float* __restrict__ eval,
                  int2* __restrict__ part, int* __restrict__ boffs)
{
    __shared__ int shist[512];
    __shared__ int sexcl[512];
    __shared__ int ssc[512];
    const int tid = threadIdx.x;
    const int blk = blockIdx.x;

    shist[tid] = 0;
    __syncthreads();

    const int base = blk * EPB;
    int rr[EPB / 512];                 // 8 cached row ids
    #pragma unroll
    for (int j = 0; j < EPB / 512; ++j) {
        const int e = base + j * 512 + tid;
        rr[j] = (e < NE) ? erow[e] : -1;
        if (rr[j] >= 0) atomicAdd(&shist[rr[j] >> 8], 1);
    }
    __syncthreads();

    const int cval = shist[tid];
    ssc[tid] = cval;
    __syncthreads();
    #pragma unroll
    for (int off = 1; off < 512; off <<= 1) {
        const int v = (tid >= off) ? ssc[tid - off] : 0;
        __syncthreads();
        ssc[tid] += v;
        __syncthreads();
    }
    const int excl = ssc[tid] - cval;
    sexcl[tid] = excl;
    if (tid < NBUCK) boffs[(size_t)blk * BOS + tid] = excl;
    if (tid == 0)    boffs[(size_t)blk * BOS + NBUCK] = ssc[511];
    __syncthreads();

    #pragma unroll
    for (int j = 0; j < EPB / 512; ++j) {
        const int r = rr[j];
        if (r >= 0) {
            const int e = base + j * 512 + tid;
            const int pos = atomicAdd(&sexcl[r >> 8], 1);
            part[(size_t)blk * EPB + pos] =
                make_int2(((r & 255) << 17) | ecol[e], __float_as_int(eval[e]));
        }
    }
}

// ---------------------------------------------------------------------------
// K2 (512 threads): blocks [0, NBUCK) = part2 (row counting sort);
//                   blocks [NBUCK, NBUCK+G0B2) = gemm0, 128 rows/block.
// part2 (scatter/latency-bound) overlaps gemm0 (stream/MFMA-bound).
// ---------------------------------------------------------------------------
__global__ __launch_bounds__(512)
void k2_kernel(const float* __restrict__ x, const u16* __restrict__ Wf,
               u16* __restrict__ Cb,
               const int* __restrict__ boffs, const int2* __restrict__ part,
               int* __restrict__ offs, int2* __restrict__ pce)
{
    __shared__ __align__(16) long long smem8[5632];   // 45056 B shared pool
    const int tid = threadIdx.x;

    if ((int)blockIdx.x < NBUCK) {
        // ---------------- part2 branch ----------------
        int2* sbuf  = (int2*)smem8;                     // BCAP int2 (36864 B)
        int* slo    = (int*)(sbuf + BCAP);              // 512
        int* sinc   = slo + 512;                        // 512
        int* scnt   = sinc + 512;                       // 256
        int* rowoff = scnt + 256;                       // 256
        int* sdata  = rowoff + 256;                     // 512
        const int b = blockIdx.x;

        // segment bounds (block-major boffs: adjacent pair per block k)
        int l0 = 0, ln = 0;
        if (tid < P1B) {
            l0 = boffs[(size_t)tid * BOS + b];
            ln = boffs[(size_t)tid * BOS + b + 1] - l0;
        }
        slo[tid] = l0; sinc[tid] = ln;
        if (tid < 256) scnt[tid] = 0;
        sdata[tid] = l0;               // gb = telescoping sum of boffs[k][b]
        __syncthreads();
        #pragma unroll
        for (int off = 256; off > 0; off >>= 1) {
            if (tid < off) sdata[tid] += sdata[tid + off];
            __syncthreads();
        }
        const int gb = sdata[0];
        __syncthreads();

        // inclusive scan over sinc[512]
        #pragma unroll
        for (int off = 1; off < 512; off <<= 1) {
            const int v = (tid >= off) ? sinc[tid - off] : 0;
            __syncthreads();
            sinc[tid] += v;
            __syncthreads();
        }
        const int cnt = sinc[511];

        // parallel gather: output index i -> segment k via binary search
        for (int i = tid; i < cnt; i += 512) {
            int k = 0;
            #pragma unroll
            for (int step = 256; step > 0; step >>= 1) {
                const int nk = k + step;
                if (nk <= 511 && sinc[nk - 1] <= i) k = nk;
            }
            const int loc = i - (k ? sinc[k - 1] : 0);
            sbuf[i] = part[(size_t)k * EPB + slo[k] + loc];
        }
        __syncthreads();

        // row histogram
        for (int i = tid; i < cnt; i += 512)
            atomicAdd(&scnt[((u32)sbuf[i].x) >> 17], 1);
        __syncthreads();

        // scan of 256 row counts (512 threads execute barriers)
        const int c = (tid < 256) ? scnt[tid] : 0;
        sdata[tid] = c;
        __syncthreads();
        #pragma unroll
        for (int off = 1; off < 256; off <<= 1) {
            const int v = (tid >= off && tid < 256) ? sdata[tid - off] : 0;
            __syncthreads();
            if (tid < 256) sdata[tid] += v;
            __syncthreads();
        }
        if (tid < 256) {
            const int excl = sdata[tid] - c;
            offs[b * RPB + tid] = gb + excl;
            rowoff[tid] = gb + excl;
        }
        __syncthreads();

        // scatter into pce's ~37KB bucket window (L2-absorbed)
        for (int i = tid; i < cnt; i += 512) {
            const int2 ev = sbuf[i];
            const int pos = atomicAdd(&rowoff[((u32)ev.x) >> 17], 1);
            pce[pos] = make_int2(ev.x & 0x1FFFF, ev.y);
        }
        return;
    }

    // ---------------- gemm0 branch: 128 rows/block ----------------
    constexpr int RS   = 136;
    constexpr int PADW = 136;
    u16* sA = (u16*)smem8;             // 128*136 u16 = 34816 B
    u16* sC = sA;
    const int w    = tid >> 6;         // 0..7
    const int lane = tid & 63;
    const int m    = lane & 15;
    const int q    = lane >> 4;
    const int rowBase = ((int)blockIdx.x - NBUCK) * 128;

    #pragma unroll
    for (int i = 0; i < 8; ++i) {
        const int g = (i * 512 + tid) * 4;
        const int r = g >> 7, c = g & 127;
        float4 v = make_float4(0.f, 0.f, 0.f, 0.f);
        if (rowBase + r < NN) v = *(const float4*)(x + (size_t)(rowBase + r) * 128 + c);
        u16* d = &sA[r * RS + c];
        d[0] = f2bf(v.x); d[1] = f2bf(v.y); d[2] = f2bf(v.z); d[3] = f2bf(v.w);
    }
    __syncthreads();

    bf16x8 afrag[4];
    #pragma unroll
    for (int kc = 0; kc < 4; ++kc)
        afrag[kc] = *(const bf16x8*)&sA[(w * 16 + m) * RS + kc * 32 + q * 8];
    __syncthreads();

    #pragma unroll
    for (int ct = 0; ct < 8; ++ct) {
        f32x4 acc = {0.f, 0.f, 0.f, 0.f};
        #pragma unroll
        for (int kc = 0; kc < 4; ++kc) {
            const bf16x8 bfr = *(const bf16x8*)(Wf + (((ct * 4 + kc) * 64) + lane) * 8);
            acc = __builtin_amdgcn_mfma_f32_16x16x32_bf16(afrag[kc], bfr, acc, 0, 0, 0);
        }
        #pragma unroll
        for (int r = 0; r < 4; ++r)
            sC[(w * 16 + q * 4 + r) * PADW + ct * 16 + m] = f2bf(acc[r]);
    }
    __syncthreads();

    const int g    = lane >> 2;
    const int cb   = (lane & 3) * 32;
    const int grow = rowBase + w * 16 + g;
    if (grow < NN) {
        #pragma unroll
        for (int i = 0; i < 4; ++i) {
            const int4 v = *(const int4*)&sC[(w * 16 + g) * PADW + cb + i * 8];
            *(int4*)(Cb + (size_t)grow * 128 + cb + i * 8) = v;
        }
    }
}

// ---------------------------------------------------------------------------
// Gather helpers (bf16 rows, fp32 accumulate).
// ---------------------------------------------------------------------------
template<int LPC>
__device__ __forceinline__ void load_row(const u16* p, u32* u) {
    if constexpr (LPC == 8) {
        const uint4 t = *(const uint4*)p;
        u[0] = t.x; u[1] = t.y; u[2] = t.z; u[3] = t.w;
    } else {
        const uint2 t = *(const uint2*)p;
        u[0] = t.x; u[1] = t.y;
    }
}

template<int LPC>
__device__ __forceinline__ void fma_row(float v, const u32* u, float* a) {
    #pragma unroll
    for (int j = 0; j < LPC / 2; ++j) {
        a[2*j]   = fmaf(v, __uint_as_float(u[j] << 16),         a[2*j]);
        a[2*j+1] = fmaf(v, __uint_as_float(u[j] & 0xffff0000u), a[2*j+1]);
    }
}

// ---------------------------------------------------------------------------
// Fused SpMM+GEMM: software-pipelined cooperative pce window load (next
// window's 128B load issued before current window's shfl/row-load block) ->
// 4-edge quads of back-to-back row loads -> relu(+residual) -> LDS A-tile
// -> mfma vs fragment-ordered Wf -> coalesced C store.
// MODE 1 also writes relu'd rows (h1) to Hout for the later residual.
// ---------------------------------------------------------------------------
template<int DO, int MODE>
__global__ __launch_bounds__(256)
void spmm_gemm(const int* __restrict__ offs, const int2* __restrict__ pce,
               const u16* __restrict__ Hb, const u16* __restrict__ Wf,
               const u16* __restrict__ Res, u16* __restrict__ Cb,
               u16* __restrict__ Hout)
{
    constexpr int RS   = 136;
    constexpr int PADW = DO + 8;
    __shared__ u16 smem[16 * 136];
    const int tid = threadIdx.x;
    const int ln  = tid & 15;
    const int rl  = tid >> 4;
    const int row = blockIdx.x * 16 + rl;

    const int s = offs[row];
    const int t = offs[row + 1];
    const u16* hbase = Hb + ln * 8;

    float a0[8], a1[8];
    #pragma unroll
    for (int j = 0; j < 8; ++j) { a0[j] = 0.f; a1[j] = 0.f; }

    int2 my = make_int2(0, 0);
    if (s + ln < t) my = pce[s + ln];
    for (int e = s; e < t; e += 16) {
        int2 nxt = make_int2(0, 0);
        if (e + 16 + ln < t) nxt = pce[e + 16 + ln];   // prefetch next window
        const int rem = t - e;
        #pragma unroll
        for (int qd = 0; qd < 4; ++qd) {
            if (qd * 4 < rem) {
                const int c0 = __shfl(my.x, qd * 4 + 0, 16);
                const int v0 = __shfl(my.y, qd * 4 + 0, 16);
                const int c1 = __shfl(my.x, qd * 4 + 1, 16);
                const int v1 = __shfl(my.y, qd * 4 + 1, 16);
                const int c2 = __shfl(my.x, qd * 4 + 2, 16);
                const int v2 = __shfl(my.y, qd * 4 + 2, 16);
                const int c3 = __shfl(my.x, qd * 4 + 3, 16);
                const int v3 = __shfl(my.y, qd * 4 + 3, 16);
                u32 u0[4], u1[4], u2[4], u3[4];
                load_row<8>(hbase + (size_t)c0 * 128, u0);
                load_row<8>(hbase + (size_t)c1 * 128, u1);
                load_row<8>(hbase + (size_t)c2 * 128, u2);
                load_row<8>(hbase + (size_t)c3 * 128, u3);
                fma_row<8>(__int_as_float(v0), u0, a0);
                fma_row<8>(__int_as_float(v1), u1, a1);
                fma_row<8>(__int_as_float(v2), u2, a0);
                fma_row<8>(__int_as_float(v3), u3, a1);
            }
        }
        my = nxt;
    }
    #pragma unroll
    for (int j = 0; j < 8; ++j) a0[j] = fmaxf(a0[j] + a1[j], 0.f);

    if constexpr (MODE == 2) {
        u32 r[4];
        load_row<8>(Res + (size_t)row * 128 + ln * 8, r);
        #pragma unroll
        for (int j = 0; j < 4; ++j) {
            a0[2*j]   += __uint_as_float(r[j] << 16);
            a0[2*j+1] += __uint_as_float(r[j] & 0xffff0000u);
        }
    }
    u32 o[4];
    #pragma unroll
    for (int j = 0; j < 4; ++j)
        o[j] = (u32)f2bf(a0[2*j]) | ((u32)f2bf(a0[2*j+1]) << 16);
    const uint4 packed = make_uint4(o[0], o[1], o[2], o[3]);
    *(uint4*)&smem[rl * RS + ln * 8] = packed;
    if constexpr (MODE == 1)
        *(uint4*)(Hout + (size_t)row * 128 + ln * 8) = packed;
    __syncthreads();

    constexpr int TPW = DO / 64;
    const int w    = tid >> 6;
    const int lane = tid & 63;
    const int m    = lane & 15;
    const int q    = lane >> 4;

    bf16x8 afrag[4];
    #pragma unroll
    for (int kc = 0; kc < 4; ++kc)
        afrag[kc] = *(const bf16x8*)&smem[m * RS + kc * 32 + q * 8];

    f32x4 acc[TPW];
    #pragma unroll
    for (int tw = 0; tw < TPW; ++tw) {
        const int ct = w * TPW + tw;
        acc[tw] = (f32x4){0.f, 0.f, 0.f, 0.f};
        #pragma unroll
        for (int kc = 0; kc < 4; ++kc) {
            const bf16x8 b = *(const bf16x8*)(Wf + (((ct * 4 + kc) * 64) + lane) * 8);
            acc[tw] = __builtin_amdgcn_mfma_f32_16x16x32_bf16(afrag[kc], b, acc[tw], 0, 0, 0);
        }
    }
    __syncthreads();

    #pragma unroll
    for (int tw = 0; tw < TPW; ++tw) {
        const int ct = w * TPW + tw;
        #pragma unroll
        for (int r = 0; r < 4; ++r)
            smem[(q * 4 + r) * PADW + ct * 16 + m] = f2bf(acc[tw][r]);
    }
    __syncthreads();

    if (DO == 128 || tid < 128) {
        const int g = tid * 8;
        const int r = g / DO;
        const int c = g % DO;
        const int4 v = *(const int4*)&smem[r * PADW + c];
        *(int4*)(Cb + ((size_t)blockIdx.x * 16 + r) * DO + c) = v;
    }
}

// ---------------------------------------------------------------------------
// Final CSR SpMM (layer 3): gather t2 (D=64), pipelined pce + shfl, fp32 out.
// ---------------------------------------------------------------------------
__global__ __launch_bounds__(256)
void spmm_out(const int* __restrict__ offs, const int2* __restrict__ pce,
              const u16* __restrict__ Hb, float* __restrict__ Y)
{
    const int ln  = threadIdx.x & 15;
    const int row = blockIdx.x * 16 + (threadIdx.x >> 4);
    if (row >= NN) return;
    const int s = offs[row];
    const int t = offs[row + 1];
    const u16* hbase = Hb + ln * 4;

    float a0[4], a1[4];
    #pragma unroll
    for (int j = 0; j < 4; ++j) { a0[j] = 0.f; a1[j] = 0.f; }

    int2 my = make_int2(0, 0);
    if (s + ln < t) my = pce[s + ln];
    for (int e = s; e < t; e += 16) {
        int2 nxt = make_int2(0, 0);
        if (e + 16 + ln < t) nxt = pce[e + 16 + ln];
        const int rem = t - e;
        #pragma unroll
        for (int qd = 0; qd < 4; ++qd) {
            if (qd * 4 < rem) {
                const int c0 = __shfl(my.x, qd * 4 + 0, 16);
                const int v0 = __shfl(my.y, qd * 4 + 0, 16);
                const int c1 = __shfl(my.x, qd * 4 + 1, 16);
                const int v1 = __shfl(my.y, qd * 4 + 1, 16);
                const int c2 = __shfl(my.x, qd * 4 + 2, 16);
                const int v2 = __shfl(my.y, qd * 4 + 2, 16);
                const int c3 = __shfl(my.x, qd * 4 + 3, 16);
                const int v3 = __shfl(my.y, qd * 4 + 3, 16);
                u32 u0[2], u1[2], u2[2], u3[2];
                load_row<4>(hbase + (size_t)c0 * 64, u0);
                load_row<4>(hbase + (size_t)c1 * 64, u1);
                load_row<4>(hbase + (size_t)c2 * 64, u2);
                load_row<4>(hbase + (size_t)c3 * 64, u3);
                fma_row<4>(__int_as_float(v0), u0, a0);
                fma_row<4>(__int_as_float(v1), u1, a1);
                fma_row<4>(__int_as_float(v2), u2, a0);
                fma_row<4>(__int_as_float(v3), u3, a1);
            }
        }
        my = nxt;
    }
    #pragma unroll
    for (int j = 0; j < 4; ++j) a0[j] += a1[j];
    *(float4*)(Y + (size_t)row * 64 + ln * 4) = make_float4(a0[0], a0[1], a0[2], a0[3]);
}

extern "C" void kernel_launch(void* const* d_in, const int* in_sizes, int n_in,
                              void* d_out, int out_size, void* d_ws, size_t ws_size,
                              hipStream_t stream) {
    const float* x    = (const float*)d_in[0];
    const int*   erow = (const int*)  d_in[1];
    const int*   ecol = (const int*)  d_in[2];
    const float* eval = (const float*)d_in[3];
    const float* W0   = (const float*)d_in[4];
    const float* W1   = (const float*)d_in[5];
    const float* W2   = (const float*)d_in[6];
    float* out = (float*)d_out;

    char* p = (char*)d_ws;
    const size_t BUFB = (size_t)NN * 128 * sizeof(u16);   // 25.6 MB
    u16* t0b  = (u16*)p;  p += BUFB;     // t0; reused for t2 (t0 dead by then)
    u16* t1b  = (u16*)p;  p += BUFB;
    u16* h1b  = (u16*)p;  p += BUFB;
    u16* wf0  = (u16*)p;  p += 128 * 128 * 2;
    u16* wf1  = (u16*)p;  p += 128 * 128 * 2;
    u16* wf2  = (u16*)p;  p += 64 * 128 * 2;
    int* boffs  = (int*)p; p += (size_t)P1B * BOS * 4;    // 615 KB (block-major)
    int* offs   = (int*)p; p += ((size_t)PAD + 256) * 4;
    int2* part  = (int2*)p; p += (size_t)P1B * EPB * 8;   // 12.81 MB
    int2* pce   = (int2*)p;                               // 12.8 MB

    const int rowBlocks = NN / 16;     // 6250

    wcvt_kernel <<<64, dim3(256), 0, stream>>>(W0, W1, W2, wf0, wf1, wf2);
    part1_kernel<<<P1B, dim3(512), 0, stream>>>(erow, ecol, eval, part, boffs);
    k2_kernel   <<<NBUCK + G0B2, dim3(512), 0, stream>>>(x, wf0, t0b, boffs, part, offs, pce);
    spmm_gemm<128, 1><<<rowBlocks, dim3(256), 0, stream>>>(offs, pce, t0b, wf1, nullptr, t1b, h1b);
    spmm_gemm<64, 2><<<rowBlocks, dim3(256), 0, stream>>>(offs, pce, t1b, wf2, h1b, t0b, nullptr);
    spmm_out<<<rowBlocks, dim3(256), 0, stream>>>(offs, pce, t0b, out);
}

// Round 12
// 309.248 us; speedup vs baseline: 1.0420x; 1.0040x over previous
//
#include <hip/hip_runtime.h>

// GCN on MI355X (gfx950). n=100000, 1.6M edges, D 128/128/64.
// Round 20: middle-kernel cuts, isolated from the R18 crash-suspect (EPB
// stays 4096).
//  - wcvt merged into part1's dispatch (k0: blocks [0,32)=wcvt 512thr,
//    [32,32+391)=part1). 6 -> 5 dispatches.
//  - part2: per-edge 8-step LDS binary search REPLACED by 16-lane-group
//    cooperative segment copy (group g copies segments g,g+32,...; avg len
//    10.4, contiguous 128B reads, zero dependent-read search).
//  - F kernels unchanged from R19 (fabric-pinned at 47% HBM; prefetch kept,
//    measured neutral).
// Pipeline: K0[wcvt||part1] -> K2[part2||gemm0] -> F1 -> F2 -> spmm_out.

typedef unsigned int u32;
typedef unsigned short u16;
typedef __attribute__((ext_vector_type(8))) short bf16x8;
typedef __attribute__((ext_vector_type(4))) float f32x4;

constexpr int NN = 100000;
constexpr int NE = 1600000;
constexpr int RPB = 256;               // rows per bucket
constexpr int NBUCK = 392;             // 392 * 256 = 100352 = PAD
constexpr int PAD = 100352;
constexpr int BCAP = 4608;             // per-bucket edges (mean 4082)
constexpr int EPB = 4096;              // edges per part1 block
constexpr int P1B = (NE + EPB - 1) / EPB;   // 391 part1 blocks
constexpr int WCB = 32;                // wcvt blocks in k0 (512 thr each)
constexpr int G0B2 = (NN + 127) / 128;      // 782 gemm0 blocks (128 rows)
constexpr int BOS = NBUCK + 1;         // boffs row stride (block-major)

__device__ __forceinline__ u16 f2bf(float f) {   // RNE round to bf16
    u32 x = __float_as_uint(f);
    x += 0x7fffu + ((x >> 16) & 1u);
    return (u16)(x >> 16);
}

// ---------------------------------------------------------------------------
// Weight fp32 -> bf16 in B-fragment order.
// ---------------------------------------------------------------------------
__device__ __forceinline__ void wfrag_one(const float* __restrict__ W,
                                          u16* __restrict__ Wf, int total, int i)
{
    if (i < total) {
        const int j    = i & 7;
        const int lane = (i >> 3) & 63;
        const int kc   = (i >> 9) & 3;
        const int ct   = i >> 11;
        const int src  = (ct * 16 + (lane & 15)) * 128 + kc * 32 + (lane >> 4) * 8 + j;
        Wf[i] = f2bf(W[src]);
    }
}

// ---------------------------------------------------------------------------
// K0 (512 threads): blocks [0, WCB) = wcvt; blocks [WCB, WCB+P1B) = part1.
// part1: block-local bucket partition, no global atomics (R19-proven body).
// ---------------------------------------------------------------------------
__global__ __launch_bounds__(512)
void k0_kernel(const float* __restrict__ W0, const float* __restrict__ W1,
               const float* __restrict__ W2, u16* __restrict__ wf0,
               u16* __restrict__ wf1, u16* __restrict__ wf2,
               const int* __restrict__ erow, const int* __restrict__ ecol,
               const float* __restrict__ eval,
               int2* __restrict__ part, int* __restrict__ boffs)
{
    __shared__ int shist[512];
    __shared__ int sexcl[512];
    __shared__ int ssc[512];
    const int tid = threadIdx.x;

    if ((int)blockIdx.x < WCB) {
        const int i = blockIdx.x * 512 + tid;    // covers 16384 = 128*128
        wfrag_one(W0, wf0, 128 * 128, i);
        wfrag_one(W1, wf1, 128 * 128, i);
        wfrag_one(W2, wf2, 64 * 128, i);
        return;
    }

    const int blk = (int)blockIdx.x - WCB;
    shist[tid] = 0;
    __syncthreads();

    const int base = blk * EPB;
    int rr[EPB / 512];                 // 8 cached row ids
    #pragma unroll
    for (int j = 0; j < EPB / 512; ++j) {
        const int e = base + j * 512 + tid;
        rr[j] = (e < NE) ? erow[e] : -1;
        if (rr[j] >= 0) atomicAdd(&shist[rr[j] >> 8], 1);
    }
    __syncthreads();

    const int cval = shist[tid];
    ssc[tid] = cval;
    __syncthreads();
    #pragma unroll
    for (int off = 1; off < 512; off <<= 1) {
        const int v = (tid >= off) ? ssc[tid - off] : 0;
        __syncthreads();
        ssc[tid] += v;
        __syncthreads();
    }
    const int excl = ssc[tid] - cval;
    sexcl[tid] = excl;
    if (tid < NBUCK) boffs[(size_t)blk * BOS + tid] = excl;
    if (tid == 0)    boffs[(size_t)blk * BOS + NBUCK] = ssc[511];
    __syncthreads();

    #pragma unroll
    for (int j = 0; j < EPB / 512; ++j) {
        const int r = rr[j];
        if (r >= 0) {
            const int e = base + j * 512 + tid;
            const int pos = atomicAdd(&sexcl[r >> 8], 1);
            part[(size_t)blk * EPB + pos] =
                make_int2(((r & 255) << 17) | ecol[e], __float_as_int(eval[e]));
        }
    }
}

// ---------------------------------------------------------------------------
// K2 (512 threads): blocks [0, NBUCK) = part2 (row counting sort);
//                   blocks [NBUCK, NBUCK+G0B2) = gemm0, 128 rows/block.
// part2 gather: 16-lane-group cooperative segment copy (no binary search).
// ---------------------------------------------------------------------------
__global__ __launch_bounds__(512)
void k2_kernel(const float* __restrict__ x, const u16* __restrict__ Wf,
               u16* __restrict__ Cb,
               const int* __restrict__ boffs, const int2* __restrict__ part,
               int* __restrict__ offs, int2* __restrict__ pce)
{
    __shared__ __align__(16) long long smem8[5632];   // 45056 B shared pool
    const int tid = threadIdx.x;

    if ((int)blockIdx.x < NBUCK) {
        // ---------------- part2 branch ----------------
        int2* sbuf  = (int2*)smem8;                     // BCAP int2 (36864 B)
        int* slo    = (int*)(sbuf + BCAP);              // 512
        int* sinc   = slo + 512;                        // 512
        int* scnt   = sinc + 512;                       // 256
        int* rowoff = scnt + 256;                       // 256
        int* sdata  = rowoff + 256;                     // 512
        const int b = blockIdx.x;

        // segment bounds (block-major boffs: adjacent pair per block k)
        int l0 = 0, ln = 0;
        if (tid < P1B) {
            l0 = boffs[(size_t)tid * BOS + b];
            ln = boffs[(size_t)tid * BOS + b + 1] - l0;
        }
        slo[tid] = l0; sinc[tid] = ln;
        if (tid < 256) scnt[tid] = 0;
        sdata[tid] = l0;               // gb = telescoping sum of boffs[k][b]
        __syncthreads();
        #pragma unroll
        for (int off = 256; off > 0; off >>= 1) {
            if (tid < off) sdata[tid] += sdata[tid + off];
            __syncthreads();
        }
        const int gb = sdata[0];
        __syncthreads();

        // inclusive scan over sinc[512]
        #pragma unroll
        for (int off = 1; off < 512; off <<= 1) {
            const int v = (tid >= off) ? sinc[tid - off] : 0;
            __syncthreads();
            sinc[tid] += v;
            __syncthreads();
        }
        const int cnt = sinc[511];

        // 16-lane-group cooperative segment copy (contiguous reads, no search)
        {
            const int grp = tid >> 4;          // 0..31
            const int gl  = tid & 15;
            for (int sg = grp; sg < P1B; sg += 32) {
                const int dst = sg ? sinc[sg - 1] : 0;
                const int len = sinc[sg] - dst;
                const int2* srcp = part + (size_t)sg * EPB + slo[sg];
                for (int i = gl; i < len; i += 16)
                    sbuf[dst + i] = srcp[i];
            }
        }
        __syncthreads();

        // row histogram
        for (int i = tid; i < cnt; i += 512)
            atomicAdd(&scnt[((u32)sbuf[i].x) >> 17], 1);
        __syncthreads();

        // scan of 256 row counts (512 threads execute barriers)
        const int c = (tid < 256) ? scnt[tid] : 0;
        sdata[tid] = c;
        __syncthreads();
        #pragma unroll
        for (int off = 1; off < 256; off <<= 1) {
            const int v = (tid >= off && tid < 256) ? sdata[tid - off] : 0;
            __syncthreads();
            if (tid < 256) sdata[tid] += v;
            __syncthreads();
        }
        if (tid < 256) {
            const int excl = sdata[tid] - c;
            offs[b * RPB + tid] = gb + excl;
            rowoff[tid] = gb + excl;
        }
        __syncthreads();

        // scatter into pce's ~37KB bucket window (L2-absorbed)
        for (int i = tid; i < cnt; i += 512) {
            const int2 ev = sbuf[i];
            const int pos = atomicAdd(&rowoff[((u32)ev.x) >> 17], 1);
            pce[pos] = make_int2(ev.x & 0x1FFFF, ev.y);
        }
        return;
    }

    // ---------------- gemm0 branch: 128 rows/block ----------------
    constexpr int RS   = 136;
    constexpr int PADW = 136;
    u16* sA = (u16*)smem8;             // 128*136 u16 = 34816 B
    u16* sC = sA;
    const int w    = tid >> 6;         // 0..7
    const int lane = tid & 63;
    const int m    = lane & 15;
    const int q    = lane >> 4;
    const int rowBase = ((int)blockIdx.x - NBUCK) * 128;

    #pragma unroll
    for (int i = 0; i < 8; ++i) {
        const int g = (i * 512 + tid) * 4;
        const int r = g >> 7, c = g & 127;
        float4 v = make_float4(0.f, 0.f, 0.f, 0.f);
        if (rowBase + r < NN) v = *(const float4*)(x + (size_t)(rowBase + r) * 128 + c);
        u16* d = &sA[r * RS + c];
        d[0] = f2bf(v.x); d[1] = f2bf(v.y); d[2] = f2bf(v.z); d[3] = f2bf(v.w);
    }
    __syncthreads();

    bf16x8 afrag[4];
    #pragma unroll
    for (int kc = 0; kc < 4; ++kc)
        afrag[kc] = *(const bf16x8*)&sA[(w * 16 + m) * RS + kc * 32 + q * 8];
    __syncthreads();

    #pragma unroll
    for (int ct = 0; ct < 8; ++ct) {
        f32x4 acc = {0.f, 0.f, 0.f, 0.f};
        #pragma unroll
        for (int kc = 0; kc < 4; ++kc) {
            const bf16x8 bfr = *(const bf16x8*)(Wf + (((ct * 4 + kc) * 64) + lane) * 8);
            acc = __builtin_amdgcn_mfma_f32_16x16x32_bf16(afrag[kc], bfr, acc, 0, 0, 0);
        }
        #pragma unroll
        for (int r = 0; r < 4; ++r)
            sC[(w * 16 + q * 4 + r) * PADW + ct * 16 + m] = f2bf(acc[r]);
    }
    __syncthreads();

    const int g    = lane >> 2;
    const int cb   = (lane & 3) * 32;
    const int grow = rowBase + w * 16 + g;
    if (grow < NN) {
        #pragma unroll
        for (int i = 0; i < 4; ++i) {
            const int4 v = *(const int4*)&sC[(w * 16 + g) * PADW + cb + i * 8];
            *(int4*)(Cb + (size_t)grow * 128 + cb + i * 8) = v;
        }
    }
}

// ---------------------------------------------------------------------------
// Gather helpers (bf16 rows, fp32 accumulate).
// ---------------------------------------------------------------------------
template<int LPC>
__device__ __forceinline__ void load_row(const u16* p, u32* u) {
    if constexpr (LPC == 8) {
        const uint4 t = *(const uint4*)p;
        u[0] = t.x; u[1] = t.y; u[2] = t.z; u[3] = t.w;
    } else {
        const uint2 t = *(const uint2*)p;
        u[0] = t.x; u[1] = t.y;
    }
}

template<int LPC>
__device__ __forceinline__ void fma_row(float v, const u32* u, float* a) {
    #pragma unroll
    for (int j = 0; j < LPC / 2; ++j) {
        a[2*j]   = fmaf(v, __uint_as_float(u[j] << 16),         a[2*j]);
        a[2*j+1] = fmaf(v, __uint_as_float(u[j] & 0xffff0000u), a[2*j+1]);
    }
}

// ---------------------------------------------------------------------------
// Fused SpMM+GEMM (R19 body): pipelined cooperative pce window load + shfl
// broadcast -> 4-edge quads -> relu(+residual) -> LDS A-tile -> mfma ->
// coalesced C store. MODE 1 also writes relu'd rows (h1) to Hout.
// ---------------------------------------------------------------------------
template<int DO, int MODE>
__global__ __launch_bounds__(256)
void spmm_gemm(const int* __restrict__ offs, const int2* __restrict__ pce,
               const u16* __restrict__ Hb, const u16* __restrict__ Wf,
               const u16* __restrict__ Res, u16* __restrict__ Cb,
               u16* __restrict__ Hout)
{
    constexpr int RS   = 136;
    constexpr int PADW = DO + 8;
    __shared__ u16 smem[16 * 136];
    const int tid = threadIdx.x;
    const int ln  = tid & 15;
    const int rl  = tid >> 4;
    const int row = blockIdx.x * 16 + rl;

    const int s = offs[row];
    const int t = offs[row + 1];
    const u16* hbase = Hb + ln * 8;

    float a0[8], a1[8];
    #pragma unroll
    for (int j = 0; j < 8; ++j) { a0[j] = 0.f; a1[j] = 0.f; }

    int2 my = make_int2(0, 0);
    if (s + ln < t) my = pce[s + ln];
    for (int e = s; e < t; e += 16) {
        int2 nxt = make_int2(0, 0);
        if (e + 16 + ln < t) nxt = pce[e + 16 + ln];   // prefetch next window
        const int rem = t - e;
        #pragma unroll
        for (int qd = 0; qd < 4; ++qd) {
            if (qd * 4 < rem) {
                const int c0 = __shfl(my.x, qd * 4 + 0, 16);
                const int v0 = __shfl(my.y, qd * 4 + 0, 16);
                const int c1 = __shfl(my.x, qd * 4 + 1, 16);
                const int v1 = __shfl(my.y, qd * 4 + 1, 16);
                const int c2 = __shfl(my.x, qd * 4 + 2, 16);
                const int v2 = __shfl(my.y, qd * 4 + 2, 16);
                const int c3 = __shfl(my.x, qd * 4 + 3, 16);
                const int v3 = __shfl(my.y, qd * 4 + 3, 16);
                u32 u0[4], u1[4], u2[4], u3[4];
                load_row<8>(hbase + (size_t)c0 * 128, u0);
                load_row<8>(hbase + (size_t)c1 * 128, u1);
                load_row<8>(hbase + (size_t)c2 * 128, u2);
                load_row<8>(hbase + (size_t)c3 * 128, u3);
                fma_row<8>(__int_as_float(v0), u0, a0);
                fma_row<8>(__int_as_float(v1), u1, a1);
                fma_row<8>(__int_as_float(v2), u2, a0);
                fma_row<8>(__int_as_float(v3), u3, a1);
            }
        }
        my = nxt;
    }
    #pragma unroll
    for (int j = 0; j < 8; ++j) a0[j] = fmaxf(a0[j] + a1[j], 0.f);

    if constexpr (MODE == 2) {
        u32 r[4];
        load_row<8>(Res + (size_t)row * 128 + ln * 8, r);
        #pragma unroll
        for (int j = 0; j < 4; ++j) {
            a0[2*j]   += __uint_as_float(r[j] << 16);
            a0[2*j+1] += __uint_as_float(r[j] & 0xffff0000u);
        }
    }
    u32 o[4];
    #pragma unroll
    for (int j = 0; j < 4; ++j)
        o[j] = (u32)f2bf(a0[2*j]) | ((u32)f2bf(a0[2*j+1]) << 16);
    const uint4 packed = make_uint4(o[0], o[1], o[2], o[3]);
    *(uint4*)&smem[rl * RS + ln * 8] = packed;
    if constexpr (MODE == 1)
        *(uint4*)(Hout + (size_t)row * 128 + ln * 8) = packed;
    __syncthreads();

    constexpr int TPW = DO / 64;
    const int w    = tid >> 6;
    const int lane = tid & 63;
    const int m    = lane & 15;
    const int q    = lane >> 4;

    bf16x8 afrag[4];
    #pragma unroll
    for (int kc = 0; kc < 4; ++kc)
        afrag[kc] = *(const bf16x8*)&smem[m * RS + kc * 32 + q * 8];

    f32x4 acc[TPW];
    #pragma unroll
    for (int tw = 0; tw < TPW; ++tw) {
        const int ct = w * TPW + tw;
        acc[tw] = (f32x4){0.f, 0.f, 0.f, 0.f};
        #pragma unroll
        for (int kc = 0; kc < 4; ++kc) {
            const bf16x8 b = *(const bf16x8*)(Wf + (((ct * 4 + kc) * 64) + lane) * 8);
            acc[tw] = __builtin_amdgcn_mfma_f32_16x16x32_bf16(afrag[kc], b, acc[tw], 0, 0, 0);
        }
    }
    __syncthreads();

    #pragma unroll
    for (int tw = 0; tw < TPW; ++tw) {
        const int ct = w * TPW + tw;
        #pragma unroll
        for (int r = 0; r < 4; ++r)
            smem[(q * 4 + r) * PADW + ct * 16 + m] = f2bf(acc[tw][r]);
    }
    __syncthreads();

    if (DO == 128 || tid < 128) {
        const int g = tid * 8;
        const int r = g / DO;
        const int c = g % DO;
        const int4 v = *(const int4*)&smem[r * PADW + c];
        *(int4*)(Cb + ((size_t)blockIdx.x * 16 + r) * DO + c) = v;
    }
}

// ---------------------------------------------------------------------------
// Final CSR SpMM (layer 3): gather t2 (D=64), pipelined pce + shfl, fp32 out.
// ---------------------------------------------------------------------------
__global__ __launch_bounds__(256)
void spmm_out(const int* __restrict__ offs, const int2* __restrict__ pce,
              const u16* __restrict__ Hb, float* __restrict__ Y)
{
    const int ln  = threadIdx.x & 15;
    const int row = blockIdx.x * 16 + (threadIdx.x >> 4);
    if (row >= NN) return;
    const int s = offs[row];
    const int t = offs[row + 1];
    const u16* hbase = Hb + ln * 4;

    float a0[4], a1[4];
    #pragma unroll
    for (int j = 0; j < 4; ++j) { a0[j] = 0.f; a1[j] = 0.f; }

    int2 my = make_int2(0, 0);
    if (s + ln < t) my = pce[s + ln];
    for (int e = s; e < t; e += 16) {
        int2 nxt = make_int2(0, 0);
        if (e + 16 + ln < t) nxt = pce[e + 16 + ln];
        const int rem = t - e;
        #pragma unroll
        for (int qd = 0; qd < 4; ++qd) {
            if (qd * 4 < rem) {
                const int c0 = __shfl(my.x, qd * 4 + 0, 16);
                const int v0 = __shfl(my.y, qd * 4 + 0, 16);
                const int c1 = __shfl(my.x, qd * 4 + 1, 16);
                const int v1 = __shfl(my.y, qd * 4 + 1, 16);
                const int c2 = __shfl(my.x, qd * 4 + 2, 16);
                const int v2 = __shfl(my.y, qd * 4 + 2, 16);
                const int c3 = __shfl(my.x, qd * 4 + 3, 16);
                const int v3 = __shfl(my.y, qd * 4 + 3, 16);
                u32 u0[2], u1[2], u2[2], u3[2];
                load_row<4>(hbase + (size_t)c0 * 64, u0);
                load_row<4>(hbase + (size_t)c1 * 64, u1);
                load_row<4>(hbase + (size_t)c2 * 64, u2);
                load_row<4>(hbase + (size_t)c3 * 64, u3);
                fma_row<4>(__int_as_float(v0), u0, a0);
                fma_row<4>(__int_as_float(v1), u1, a1);
                fma_row<4>(__int_as_float(v2), u2, a0);
                fma_row<4>(__int_as_float(v3), u3, a1);
            }
        }
        my = nxt;
    }
    #pragma unroll
    for (int j = 0; j < 4; ++j) a0[j] += a1[j];
    *(float4*)(Y + (size_t)row * 64 + ln * 4) = make_float4(a0[0], a0[1], a0[2], a0[3]);
}

extern "C" void kernel_launch(void* const* d_in, const int* in_sizes, int n_in,
                              void* d_out, int out_size, void* d_ws, size_t ws_size,
                              hipStream_t stream) {
    const float* x    = (const float*)d_in[0];
    const int*   erow = (const int*)  d_in[1];
    const int*   ecol = (const int*)  d_in[2];
    const float* eval = (const float*)d_in[3];
    const float* W0   = (const float*)d_in[4];
    const float* W1   = (const float*)d_in[5];
    const float* W2   = (const float*)d_in[6];
    float* out = (float*)d_out;

    char* p = (char*)d_ws;
    const size_t BUFB = (size_t)NN * 128 * sizeof(u16);   // 25.6 MB
    u16* t0b  = (u16*)p;  p += BUFB;     // t0; reused for t2 (t0 dead by then)
    u16* t1b  = (u16*)p;  p += BUFB;
    u16* h1b  = (u16*)p;  p += BUFB;
    u16* wf0  = (u16*)p;  p += 128 * 128 * 2;
    u16* wf1  = (u16*)p;  p += 128 * 128 * 2;
    u16* wf2  = (u16*)p;  p += 64 * 128 * 2;
    int* boffs  = (int*)p; p += (size_t)P1B * BOS * 4;    // 615 KB (block-major)
    int* offs   = (int*)p; p += ((size_t)PAD + 256) * 4;
    int2* part  = (int2*)p; p += (size_t)P1B * EPB * 8;   // 12.81 MB
    int2* pce   = (int2*)p;                               // 12.8 MB

    const int rowBlocks = NN / 16;     // 6250

    k0_kernel<<<WCB + P1B, dim3(512), 0, stream>>>(W0, W1, W2, wf0, wf1, wf2,
                                                   erow, ecol, eval, part, boffs);
    k2_kernel<<<NBUCK + G0B2, dim3(512), 0, stream>>>(x, wf0, t0b, boffs, part, offs, pce);
    spmm_gemm<128, 1><<<rowBlocks, dim3(256), 0, stream>>>(offs, pce, t0b, wf1, nullptr, t1b, h1b);
    spmm_gemm<64, 2><<<rowBlocks, dim3(256), 0, stream>>>(offs, pce, t1b, wf2, h1b, t0b, nullptr);
    spmm_out<<<rowBlocks, dim3(256), 0, stream>>>(offs, pce, t0b, out);
}